// Round 17
// baseline (271.476 us; speedup 1.0000x reference)
//
#include <hip/hip_runtime.h>
#include <hip/hip_bf16.h>

// ROUND 29: free V-transpose — gemm1 scatters v-channels to dense Vt[bh][d][t];
// attn stages V via gll16 like K (all attn ds_writes + V VALU deleted).
// Contract (R11 PASS): inputs fp32 dict-order, output fp32, shown interleaved
// split (head h owns qkv channels [h*192,(h+1)*192)), scale 1/8,
// out = att_v @ W_out^T + b_out. ws: qkv [b*16+h][t][192] bf16.
// Ladder: R13 swizzle | R14 HW cvt/exp | R15 swapped-QK^T | R16 gll16 GEMM +
// bf16 prepass | R18 Q-prescale + MFMA row-sum | R19 8-wave | R20 32 q-rows |
// R22 zero-C | R23 GEMM dbuf | R28 best-known 261.1us (attn 90: Mfma 36%,
// VALU 51%, 8 ds_write + ~30 VALU/iter/thread of V-staging left).
// R29 (local dataflow, no sync edits): stage-1 epilogue writes v (r>=128) to
// Vt[((b*16+h)*64+d)*T + t] — same store count, BETTER coalescing (contiguous
// in t by reg) — instead of the interleaved v-slot. attn V-staging becomes
// 1 gll16/wave with the same audited inverse-swizzle as Ks (row&7==lr).
// ws stays 88 MiB (proven): Vt replaces the neutral avd at +72MiB; gemm3
// back to QSLOT gather (measured neutral vs dense). Bit-identical numerics.

typedef unsigned short u16;
typedef short bf16x8 __attribute__((ext_vector_type(8)));   // 8 bf16 = 4 VGPRs
typedef float floatx4 __attribute__((ext_vector_type(4)));

#define BB 4
#define TT 2048
#define CC 1024
#define HH 16
#define CEXP 0.18033688f    // log2(e)/8 : exp(s/8) = exp2(s*CEXP)

#if __has_builtin(__builtin_amdgcn_exp2f)
#define EXP2(x) __builtin_amdgcn_exp2f(x)
#else
#define EXP2(x) exp2f(x)
#endif

__device__ __forceinline__ u16 f2bf(float f) {
    __hip_bfloat16 h = __float2bfloat16(f);
    u16 r; __builtin_memcpy(&r, &h, 2); return r;
}
__device__ __forceinline__ unsigned pkbf(float lo, float hi) {
    __hip_bfloat162 h2 = __float22bfloat162_rn(float2{lo, hi});
    unsigned r; __builtin_memcpy(&r, &h2, 4); return r;
}
__device__ __forceinline__ bf16x8 cvt8(const float* p) {
    floatx4 a = *(const floatx4*)p;
    floatx4 b = *(const floatx4*)(p + 4);
    bf16x8 r;
    r[0] = (short)f2bf(a[0]); r[1] = (short)f2bf(a[1]);
    r[2] = (short)f2bf(a[2]); r[3] = (short)f2bf(a[3]);
    r[4] = (short)f2bf(b[0]); r[5] = (short)f2bf(b[1]);
    r[6] = (short)f2bf(b[2]); r[7] = (short)f2bf(b[3]);
    return r;
}
// XOR-swizzled u16 index into a [R][64] u16 tile for a 16B slot (slot=0..7).
__device__ __forceinline__ int sw8(int row, int slot) {
    return row * 64 + (((slot ^ (row & 7)) & 7) << 3);
}
// async global->LDS, 16B/lane: dest = lds + lane*16 (wave-uniform base).
__device__ __forceinline__ void gll16(const u16* g, u16* l) {
    __builtin_amdgcn_global_load_lds(
        (const __attribute__((address_space(1))) unsigned*)g,
        (__attribute__((address_space(3))) unsigned*)l, 16, 0, 0);
}

// ---- cross-lane half swaps (gfx950 permlane*_swap, shfl fallback) ----
__device__ __forceinline__ void pl32swap(unsigned& a, unsigned& b) {
#if __has_builtin(__builtin_amdgcn_permlane32_swap)
    typedef unsigned u32x2 __attribute__((ext_vector_type(2)));
    u32x2 r = __builtin_amdgcn_permlane32_swap(a, b, false, false);
    a = r[0]; b = r[1];
#else
    const bool up = (threadIdx.x & 32) != 0;
    unsigned as = (unsigned)__shfl_xor((int)a, 32);
    unsigned bs = (unsigned)__shfl_xor((int)b, 32);
    unsigned na = up ? bs : a;
    unsigned nb = up ? b : as;
    a = na; b = nb;
#endif
}
__device__ __forceinline__ void pl16swap(unsigned& a, unsigned& b) {
#if __has_builtin(__builtin_amdgcn_permlane16_swap)
    typedef unsigned u32x2 __attribute__((ext_vector_type(2)));
    u32x2 r = __builtin_amdgcn_permlane16_swap(a, b, false, false);
    a = r[0]; b = r[1];
#else
    const bool up = (threadIdx.x & 16) != 0;
    unsigned as = (unsigned)__shfl_xor((int)a, 16);
    unsigned bs = (unsigned)__shfl_xor((int)b, 16);
    unsigned na = up ? bs : a;
    unsigned nb = up ? b : as;
    a = na; b = nb;
#endif
}

// ---------------- prepass: fp32 -> bf16 (x, W_qkv, W_out) -------------------------
__global__ __launch_bounds__(256) void cvt_all(const float* __restrict__ x,
                                               const float* __restrict__ wq,
                                               const float* __restrict__ wo,
                                               u16* __restrict__ xb,
                                               u16* __restrict__ wqb,
                                               u16* __restrict__ wob) {
    const int nx8 = 8388608 / 8, nq8 = 3145728 / 8, no8 = 1048576 / 8;
    const int n8 = nx8 + nq8 + no8;
    for (int i = blockIdx.x * blockDim.x + threadIdx.x; i < n8;
         i += gridDim.x * blockDim.x) {
        const float* src;
        u16* dst;
        if (i < nx8)            { src = x  + (size_t)i * 8;          dst = xb  + (size_t)i * 8; }
        else if (i < nx8 + nq8) { size_t j = i - nx8; src = wq + j * 8; dst = wqb + j * 8; }
        else                    { size_t j = i - nx8 - nq8; src = wo + j * 8; dst = wob + j * 8; }
        floatx4 a = *(const floatx4*)src;
        floatx4 b = *(const floatx4*)(src + 4);
        union { bf16x8 v; unsigned u[4]; } r;
        r.u[0] = pkbf(a[0], a[1]); r.u[1] = pkbf(a[2], a[3]);
        r.u[2] = pkbf(b[0], b[1]); r.u[3] = pkbf(b[2], b[3]);
        *(bf16x8*)dst = r.v;
    }
}

// ---------------- GEMM (bf16 inputs, gll16 staging, 2-phase dbuf) -----------------
// SCATTER=1: prescales q channels (r<64) by CEXP; if Vt != nullptr, v channels
// (r>=128) go to dense Vt[bh][d][t] instead of the qkv v-slot.
// QSLOT=1: A gathered from q-slots.
template <int SCATTER, int QSLOT>
__global__ __launch_bounds__(256) void gemm_lds(const u16* __restrict__ Ab,
                                                const u16* __restrict__ Bb,
                                                const float* __restrict__ bias,
                                                void* __restrict__ Cv,
                                                int K, int N,
                                                u16* __restrict__ Vt) {
    __shared__ u16 As[2][128 * 64];   // 32 KB (2 buffers)
    __shared__ u16 Bs[2][128 * 64];   // 32 KB

    const int tid  = threadIdx.x;
    const int lane = tid & 63;
    const int wave = tid >> 6;
    const int quad = lane >> 4;
    const int l15  = lane & 15;
    const int wm   = (wave >> 1) * 64;
    const int wn   = (wave & 1) * 64;
    const int blockM = blockIdx.y * 128;
    const int blockN = blockIdx.x * 128;

    floatx4 acc[4][4];
#pragma unroll
    for (int i = 0; i < 4; i++)
#pragma unroll
        for (int j = 0; j < 4; j++) acc[i][j] = (floatx4){0.f, 0.f, 0.f, 0.f};

    const int lr = lane >> 3;                       // row within 8-row chunk
    const int scol = ((lane & 7) ^ (lr & 7)) * 8;   // inverse-swizzled source col

    auto stage = [&](int buf, int k0) {
#pragma unroll
        for (int i = 0; i < 4; i++) {
            const int c = wave * 4 + i;             // chunk 0..15
            const int row = blockM + c * 8 + lr;
            const u16* src;
            if (QSLOT) {   // A = att_v in q-slots: k0 selects head (BK==hs==64)
                const int b = row >> 11, t = row & 2047, h = k0 >> 6;
                src = Ab + ((size_t)((b * HH + h) * TT + t)) * 192 + scol;
            } else {
                src = Ab + (size_t)row * K + k0 + scol;
            }
            gll16(src, &As[buf][c * 512]);
        }
#pragma unroll
        for (int i = 0; i < 4; i++) {
            const int c = wave * 4 + i;
            const int row = blockN + c * 8 + lr;
            gll16(Bb + (size_t)row * K + k0 + scol, &Bs[buf][c * 512]);
        }
    };

    stage(0, 0);
    __syncthreads();   // implicit vmcnt(0): buf0 ready

    int cur = 0;
    for (int k0 = 0; k0 < K; k0 += 64) {
        if (k0 + 64 < K) stage(cur ^ 1, k0 + 64);   // DMA next tile -> other buf

#pragma unroll
        for (int ks = 0; ks < 2; ks++) {
            const int slot = ks * 4 + quad;
            bf16x8 af[4], bfr[4];
#pragma unroll
            for (int mi = 0; mi < 4; mi++)
                af[mi] = *(const bf16x8*)&As[cur][sw8(wm + mi * 16 + l15, slot)];
#pragma unroll
            for (int ni = 0; ni < 4; ni++)
                bfr[ni] = *(const bf16x8*)&Bs[cur][sw8(wn + ni * 16 + l15, slot)];
#pragma unroll
            for (int mi = 0; mi < 4; mi++)
#pragma unroll
                for (int ni = 0; ni < 4; ni++)
                    acc[mi][ni] = __builtin_amdgcn_mfma_f32_16x16x32_bf16(
                        af[mi], bfr[ni], acc[mi][ni], 0, 0, 0);
        }

        __syncthreads();   // drains my DMA + all waves' reads of cur
        cur ^= 1;
    }

    // epilogue: C/D layout col = lane&15, row = quad*4 + reg
#pragma unroll
    for (int ni = 0; ni < 4; ni++) {
        const int col = blockN + wn + ni * 16 + l15;
        const float bv = bias[col];
        if (SCATTER) {
            const int h = col / 192;
            const int r = col - h * 192;
            u16* C = (u16*)Cv;
            if (Vt && r >= 128) {        // v channel -> dense Vt[bh][d][t]
                const int d = r - 128;
#pragma unroll
                for (int mi = 0; mi < 4; mi++)
#pragma unroll
                    for (int reg = 0; reg < 4; reg++) {
                        const int row = blockM + wm + mi * 16 + quad * 4 + reg;
                        const int b = row >> 11, t = row & 2047;
                        Vt[((size_t)(b * HH + h) * 64 + d) * TT + t] =
                            f2bf(acc[mi][ni][reg] + bv);
                    }
            } else {
                const float qs = (r < 64) ? CEXP : 1.0f;   // prescale q channels
#pragma unroll
                for (int mi = 0; mi < 4; mi++)
#pragma unroll
                    for (int reg = 0; reg < 4; reg++) {
                        const int row = blockM + wm + mi * 16 + quad * 4 + reg;
                        const int b = row >> 11, t = row & 2047;
                        C[((size_t)((b * HH + h) * TT + t)) * 192 + r] =
                            f2bf((acc[mi][ni][reg] + bv) * qs);
                    }
            }
        } else {
            float* C = (float*)Cv;
#pragma unroll
            for (int mi = 0; mi < 4; mi++)
#pragma unroll
                for (int reg = 0; reg < 4; reg++) {
                    const int row = blockM + wm + mi * 16 + quad * 4 + reg;
                    C[(size_t)row * N + col] = acc[mi][ni][reg] + bv;
                }
        }
    }
}

// ---------------- GEMM fallback (fp32 inputs, register staging) -------------------
template <int SCATTER, int QSLOT>
__global__ __launch_bounds__(256) void gemm_bt(const void* __restrict__ Av,
                                               const float* __restrict__ Bw,
                                               const float* __restrict__ bias,
                                               void* __restrict__ Cv,
                                               int K, int N) {
    __shared__ u16 As[128 * 64];
    __shared__ u16 Bs[128 * 64];

    const int tid  = threadIdx.x;
    const int lane = tid & 63;
    const int wave = tid >> 6;
    const int quad = lane >> 4;
    const int l15  = lane & 15;
    const int wm   = (wave >> 1) * 64;
    const int wn   = (wave & 1) * 64;
    const int blockM = blockIdx.y * 128;
    const int blockN = blockIdx.x * 128;

    floatx4 acc[4][4];
#pragma unroll
    for (int i = 0; i < 4; i++)
#pragma unroll
        for (int j = 0; j < 4; j++) acc[i][j] = (floatx4){0.f, 0.f, 0.f, 0.f};

    const int srow = lane >> 3;
    const int scol = (lane & 7) * 8;

    for (int k0 = 0; k0 < K; k0 += 64) {
        bf16x8 at[4], bt[4];
#pragma unroll
        for (int i = 0; i < 4; i++) {
            const int row = blockM + (i * 4 + wave) * 8 + srow;
            if (QSLOT) {
                const int b = row >> 11, t = row & 2047, h = k0 >> 6;
                at[i] = *(const bf16x8*)((const u16*)Av
                         + ((size_t)((b * HH + h) * TT + t)) * 192 + scol);
            } else {
                at[i] = cvt8((const float*)Av + (size_t)row * K + k0 + scol);
            }
        }
#pragma unroll
        for (int i = 0; i < 4; i++)
            bt[i] = cvt8(Bw + (size_t)(blockN + (i * 4 + wave) * 8 + srow) * K + k0 + scol);

        __syncthreads();
#pragma unroll
        for (int i = 0; i < 4; i++)
            *(bf16x8*)&As[sw8((i * 4 + wave) * 8 + srow, lane & 7)] = at[i];
#pragma unroll
        for (int i = 0; i < 4; i++)
            *(bf16x8*)&Bs[sw8((i * 4 + wave) * 8 + srow, lane & 7)] = bt[i];
        __syncthreads();

#pragma unroll
        for (int ks = 0; ks < 2; ks++) {
            const int slot = ks * 4 + quad;
            bf16x8 af[4], bfr[4];
#pragma unroll
            for (int mi = 0; mi < 4; mi++)
                af[mi] = *(const bf16x8*)&As[sw8(wm + mi * 16 + l15, slot)];
#pragma unroll
            for (int ni = 0; ni < 4; ni++)
                bfr[ni] = *(const bf16x8*)&Bs[sw8(wn + ni * 16 + l15, slot)];
#pragma unroll
            for (int mi = 0; mi < 4; mi++)
#pragma unroll
                for (int ni = 0; ni < 4; ni++)
                    acc[mi][ni] = __builtin_amdgcn_mfma_f32_16x16x32_bf16(
                        af[mi], bfr[ni], acc[mi][ni], 0, 0, 0);
        }
    }

#pragma unroll
    for (int ni = 0; ni < 4; ni++) {
        const int col = blockN + wn + ni * 16 + l15;
        const float bv = bias[col];
        if (SCATTER) {
            const int h = col / 192;
            const int r = col - h * 192;
            const float qs = (r < 64) ? CEXP : 1.0f;
            u16* C = (u16*)Cv;
#pragma unroll
            for (int mi = 0; mi < 4; mi++)
#pragma unroll
                for (int reg = 0; reg < 4; reg++) {
                    const int row = blockM + wm + mi * 16 + quad * 4 + reg;
                    const int b = row >> 11, t = row & 2047;
                    C[((size_t)((b * HH + h) * TT + t)) * 192 + r] =
                        f2bf((acc[mi][ni][reg] + bv) * qs);
                }
        } else {
            float* C = (float*)Cv;
#pragma unroll
            for (int mi = 0; mi < 4; mi++)
#pragma unroll
                for (int reg = 0; reg < 4; reg++) {
                    const int row = blockM + wm + mi * 16 + quad * 4 + reg;
                    C[(size_t)row * N + col] = acc[mi][ni][reg] + bv;
                }
        }
    }
}

// ---------------- Flash attention (8 waves x 32 q-rows, swapped QK^T) -------------
// 512 threads, 256-row Q tile, Bc=64. Q pre-scaled by CEXP. K: 1 gll16/thread.
// Vt != nullptr: V staged via 1 gll16/thread from dense Vt[bh][d][t]
// (zero V VALU / ds_writes); else R26 transpose-write path.
// Row-sum l via MFMA vs ones. Zero-C init. att_v -> q-slot in place.
__global__ __launch_bounds__(512) void attn_fwd(u16* __restrict__ qkv,
                                                const u16* __restrict__ Vt) {
    __shared__ u16 Ks[64 * 64];        // 8 KB  K-tile  [s][d]   (swizzled)
    __shared__ u16 Vts[64 * 64];       // 8 KB  V-tile transposed [d][s] (swizzled)

    const int tid  = threadIdx.x;
    const int lane = tid & 63;
    const int wave = tid >> 6;         // 0..7
    const int quad = lane >> 4;
    const int l15  = lane & 15;

    const int bh = blockIdx.y;
    const int t0 = blockIdx.x * 256;
    u16* Qg = qkv + (size_t)bh * TT * 192;
    const u16* VtB = Vt ? Vt + (size_t)bh * 64 * TT : nullptr;

    bf16x8 qf[2][2];
#pragma unroll
    for (int qi = 0; qi < 2; qi++) {
        const int trow = t0 + wave * 32 + qi * 16 + l15;
#pragma unroll
        for (int ks = 0; ks < 2; ks++)
            qf[qi][ks] = *(const bf16x8*)(Qg + (size_t)trow * 192 + ks * 32 + quad * 8);
    }

    bf16x8 ones;
#pragma unroll
    for (int j = 0; j < 8; j++) ones[j] = (short)0x3F80;   // bf16 1.0
    const floatx4 zero4 = (floatx4){0.f, 0.f, 0.f, 0.f};

    floatx4 o[2][4];
#pragma unroll
    for (int qi = 0; qi < 2; qi++)
#pragma unroll
        for (int di = 0; di < 4; di++) o[qi][di] = (floatx4){0.f, 0.f, 0.f, 0.f};
    floatx4 l_acc[2] = {(floatx4){0.f,0.f,0.f,0.f}, (floatx4){0.f,0.f,0.f,0.f}};

    const int lr = lane >> 3;
    const int scolsw = ((lane & 7) ^ (lr & 7)) * 8;   // inverse-swizzled col
    const int vs  = tid & 63;          // V staging (fallback): s = tid&63
    const int vd0 = (tid >> 6) * 8;    // V staging (fallback): 8-d band per wave

    for (int s0 = 0; s0 < TT; s0 += 64) {
        bf16x8 v0;
        if (!Vt)   // fallback: V load into registers before the barrier
            v0 = *(const bf16x8*)(Qg + (size_t)(s0 + vs) * 192 + 128 + vd0);

        __syncthreads();   // previous iteration's Ks/Vts readers done
        // K via async DMA (1 chunk/wave)
        gll16(Qg + (size_t)(s0 + wave * 8 + lr) * 192 + 64 + scolsw,
              &Ks[wave * 512]);
        if (Vt) {
            // V via async DMA from dense Vt: rows d = wave*8+lr, cols s0+..
            gll16(VtB + (size_t)(wave * 8 + lr) * TT + s0 + scolsw,
                  &Vts[wave * 512]);
        } else {
            const int vslot = vs >> 3, voff = vs & 7;
#pragma unroll
            for (int j = 0; j < 8; j++) {
                const int row = vd0 + j;
                Vts[row * 64 + (((vslot ^ (row & 7)) & 7) << 3) + voff] = (u16)v0[j];
            }
        }
        __syncthreads();   // drains vmcnt (DMAs) + lgkm (fallback V writes)

        // S^T = K @ Q' : lane = S'[s=si*16+quad*4+reg][q=wave*32+qi*16+l15]
        floatx4 s_acc[4][2];
        __builtin_amdgcn_s_setprio(1);
        {
            bf16x8 kf[4];
#pragma unroll
            for (int si = 0; si < 4; si++)
                kf[si] = *(const bf16x8*)&Ks[sw8(si * 16 + l15, quad)];
#pragma unroll
            for (int si = 0; si < 4; si++)
#pragma unroll
                for (int qi = 0; qi < 2; qi++)
                    s_acc[si][qi] = __builtin_amdgcn_mfma_f32_16x16x32_bf16(
                        kf[si], qf[qi][0], zero4, 0, 0, 0);
        }
        {
            bf16x8 kf[4];
#pragma unroll
            for (int si = 0; si < 4; si++)
                kf[si] = *(const bf16x8*)&Ks[sw8(si * 16 + l15, 4 + quad)];
#pragma unroll
            for (int si = 0; si < 4; si++)
#pragma unroll
                for (int qi = 0; qi < 2; qi++)
                    s_acc[si][qi] = __builtin_amdgcn_mfma_f32_16x16x32_bf16(
                        kf[si], qf[qi][1], s_acc[si][qi], 0, 0, 0);
        }
        __builtin_amdgcn_s_setprio(0);

        // P = exp2(S') in-register; pack bf16 pairs (no mul — Q pre-scaled)
        unsigned c[4][2][2];
#pragma unroll
        for (int si = 0; si < 4; si++)
#pragma unroll
            for (int qi = 0; qi < 2; qi++) {
                floatx4 p;
#pragma unroll
                for (int r = 0; r < 4; r++) p[r] = EXP2(s_acc[si][qi][r]);
                c[si][qi][0] = pkbf(p[0], p[1]);
                c[si][qi][1] = pkbf(p[2], p[3]);
            }

        // redistribute C/D-layout P -> A-fragments pf[qi][ks]
        union PF { bf16x8 v; unsigned u[4]; } pf[2][2];
#pragma unroll
        for (int qi = 0; qi < 2; qi++)
#pragma unroll
            for (int ks = 0; ks < 2; ks++)
#pragma unroll
                for (int h = 0; h < 2; h++) {
                    unsigned a = c[2 * ks][qi][h];
                    unsigned b = c[2 * ks + 1][qi][h];
                    pl32swap(a, b);
                    pl16swap(a, b);
                    pf[qi][ks].u[h]     = a;
                    pf[qi][ks].u[2 + h] = b;
                }

        // O += P @ V ; l += P @ ones (row-sum on the MFMA pipe)
        __builtin_amdgcn_s_setprio(1);
#pragma unroll
        for (int ks = 0; ks < 2; ks++) {
            const int slot = ks * 4 + quad;
            bf16x8 vf[4];
#pragma unroll
            for (int di = 0; di < 4; di++)
                vf[di] = *(const bf16x8*)&Vts[sw8(di * 16 + l15, slot)];
#pragma unroll
            for (int qi = 0; qi < 2; qi++) {
#pragma unroll
                for (int di = 0; di < 4; di++)
                    o[qi][di] = __builtin_amdgcn_mfma_f32_16x16x32_bf16(
                        pf[qi][ks].v, vf[di], o[qi][di], 0, 0, 0);
                l_acc[qi] = __builtin_amdgcn_mfma_f32_16x16x32_bf16(
                    pf[qi][ks].v, ones, l_acc[qi], 0, 0, 0);
            }
        }
        __builtin_amdgcn_s_setprio(0);
    }

    // normalize, write att_v (bf16) into the q-slot — own rows only.
#pragma unroll
    for (int qi = 0; qi < 2; qi++)
#pragma unroll
        for (int reg = 0; reg < 4; reg++) {
            const float inv_l = 1.0f / l_acc[qi][reg];
            const int trow = t0 + wave * 32 + qi * 16 + quad * 4 + reg;
#pragma unroll
            for (int di = 0; di < 4; di++)
                Qg[(size_t)trow * 192 + di * 16 + l15] = f2bf(o[qi][di][reg] * inv_l);
        }
}

extern "C" void kernel_launch(void* const* d_in, const int* in_sizes, int n_in,
                              void* d_out, int out_size, void* d_ws, size_t ws_size,
                              hipStream_t stream) {
    (void)out_size;
    float* out = (float*)d_out;

    const float *x = nullptr, *wq = nullptr, *bq = nullptr, *wo = nullptr, *bo = nullptr;
    int found = 0;
    for (int i = 0; i < n_in && i < 8; i++) {
        switch (in_sizes[i]) {
            case 8388608: x  = (const float*)d_in[i]; found |= 1;  break;
            case 3145728: wq = (const float*)d_in[i]; found |= 2;  break;
            case 3072:    bq = (const float*)d_in[i]; found |= 4;  break;
            case 1048576: wo = (const float*)d_in[i]; found |= 8;  break;
            case 1024:    bo = (const float*)d_in[i]; found |= 16; break;
        }
    }
    if (found != 31) {
        x  = (const float*)d_in[0]; wq = (const float*)d_in[1];
        bq = (const float*)d_in[2]; wo = (const float*)d_in[3];
        bo = (const float*)d_in[4];
    }

    u16* qkv = (u16*)d_ws;   // 48 MiB qkv ws

    const dim3 g1(3 * CC / 128, BB * TT / 128), ga(TT / 256, BB * HH),
               g3(CC / 128, BB * TT / 128);

    if (ws_size >= 92274688u) {   // 88 MiB: qkv48 + xb16 + wqb6 + wob2 + Vt16
        u16* xb  = qkv + 25165824;   // 48 MiB
        u16* wqb = qkv + 33554432;   // 64 MiB
        u16* wob = qkv + 36700160;   // 70 MiB
        u16* Vt  = qkv + 37748736;   // 72 MiB (64 bh x 64 d x 2048 t bf16)
        cvt_all<<<2048, 256, 0, stream>>>(x, wq, wo, xb, wqb, wob);
        gemm_lds<1, 0><<<g1, 256, 0, stream>>>(xb, wqb, bq, qkv, CC, 3 * CC, Vt);
        attn_fwd<<<ga, 512, 0, stream>>>(qkv, Vt);
        gemm_lds<0, 1><<<g3, 256, 0, stream>>>(qkv, wob, bo, out, CC, CC, nullptr);
    } else if (ws_size >= 75497472u) {   // 72 MiB: R28 path (no Vt)
        u16* xb  = qkv + 25165824;
        u16* wqb = qkv + 33554432;
        u16* wob = qkv + 36700160;
        cvt_all<<<2048, 256, 0, stream>>>(x, wq, wo, xb, wqb, wob);
        gemm_lds<1, 0><<<g1, 256, 0, stream>>>(xb, wqb, bq, qkv, CC, 3 * CC, nullptr);
        attn_fwd<<<ga, 512, 0, stream>>>(qkv, nullptr);
        gemm_lds<0, 1><<<g3, 256, 0, stream>>>(qkv, wob, bo, out, CC, CC, nullptr);
    } else {                              // register-staged fallback
        gemm_bt<1, 0><<<g1, 256, 0, stream>>>(x, wq, bq, qkv, CC, 3 * CC);
        attn_fwd<<<ga, 512, 0, stream>>>(qkv, nullptr);
        gemm_bt<0, 1><<<g3, 256, 0, stream>>>(qkv, wo, bo, out, CC, CC);
    }
}

// Round 18
// 259.114 us; speedup vs baseline: 1.0477x; 1.0477x over previous
//
#include <hip/hip_runtime.h>
#include <hip/hip_bf16.h>

// ROUND 30: revert R29 (Vt scatter REGRESSED +10us: Vt stores stride TT*2B
// across l15 lanes — 4KB-stride scatter, worse than the 384B v-slot; attn
// V-DMA saved ~nothing since staging wasn't attn's critical path).
// Final = R28 best-known configuration (261.1us, verified twice).
// Contract (R11 PASS): inputs fp32 dict-order, output fp32, shown interleaved
// split (head h owns qkv channels [h*192,(h+1)*192)), scale 1/8,
// out = att_v @ W_out^T + b_out. ws: qkv [b*16+h][t][192] bf16.
// Session ladder (425.7 -> 261.1 us, -39%):
//  R13 LDS XOR-swizzle (conflicts 3.99e7->0) | R14 HW bf16 cvt + raw v_exp |
//  R15 swapped-QK^T in-register P (permlane) | R16 gll16 GEMM + bf16 prepass |
//  R18 Q-prescale + MFMA row-sum | R19 8-wave attn | R20 32 q-rows/wave |
//  R22 zero-C init | R23 GEMM 2-phase dbuf | R26 dense att_v.
// Reverted regressions: R17 XCD-swizzle/transpose_v, R21 128-wide stage,
// R24 attn dbuf, R27 64 q-rows, R29 Vt scatter. Remaining headroom (attn
// Mfma 36%) requires full 8-phase counted-vmcnt co-design (not incremental).

typedef unsigned short u16;
typedef short bf16x8 __attribute__((ext_vector_type(8)));   // 8 bf16 = 4 VGPRs
typedef float floatx4 __attribute__((ext_vector_type(4)));

#define BB 4
#define TT 2048
#define CC 1024
#define HH 16
#define CEXP 0.18033688f    // log2(e)/8 : exp(s/8) = exp2(s*CEXP)

#if __has_builtin(__builtin_amdgcn_exp2f)
#define EXP2(x) __builtin_amdgcn_exp2f(x)
#else
#define EXP2(x) exp2f(x)
#endif

__device__ __forceinline__ u16 f2bf(float f) {
    __hip_bfloat16 h = __float2bfloat16(f);
    u16 r; __builtin_memcpy(&r, &h, 2); return r;
}
__device__ __forceinline__ unsigned pkbf(float lo, float hi) {
    __hip_bfloat162 h2 = __float22bfloat162_rn(float2{lo, hi});
    unsigned r; __builtin_memcpy(&r, &h2, 4); return r;
}
__device__ __forceinline__ bf16x8 cvt8(const float* p) {
    floatx4 a = *(const floatx4*)p;
    floatx4 b = *(const floatx4*)(p + 4);
    bf16x8 r;
    r[0] = (short)f2bf(a[0]); r[1] = (short)f2bf(a[1]);
    r[2] = (short)f2bf(a[2]); r[3] = (short)f2bf(a[3]);
    r[4] = (short)f2bf(b[0]); r[5] = (short)f2bf(b[1]);
    r[6] = (short)f2bf(b[2]); r[7] = (short)f2bf(b[3]);
    return r;
}
// XOR-swizzled u16 index into a [R][64] u16 tile for a 16B slot (slot=0..7).
__device__ __forceinline__ int sw8(int row, int slot) {
    return row * 64 + (((slot ^ (row & 7)) & 7) << 3);
}
// async global->LDS, 16B/lane: dest = lds + lane*16 (wave-uniform base).
__device__ __forceinline__ void gll16(const u16* g, u16* l) {
    __builtin_amdgcn_global_load_lds(
        (const __attribute__((address_space(1))) unsigned*)g,
        (__attribute__((address_space(3))) unsigned*)l, 16, 0, 0);
}

// ---- cross-lane half swaps (gfx950 permlane*_swap, shfl fallback) ----
__device__ __forceinline__ void pl32swap(unsigned& a, unsigned& b) {
#if __has_builtin(__builtin_amdgcn_permlane32_swap)
    typedef unsigned u32x2 __attribute__((ext_vector_type(2)));
    u32x2 r = __builtin_amdgcn_permlane32_swap(a, b, false, false);
    a = r[0]; b = r[1];
#else
    const bool up = (threadIdx.x & 32) != 0;
    unsigned as = (unsigned)__shfl_xor((int)a, 32);
    unsigned bs = (unsigned)__shfl_xor((int)b, 32);
    unsigned na = up ? bs : a;
    unsigned nb = up ? b : as;
    a = na; b = nb;
#endif
}
__device__ __forceinline__ void pl16swap(unsigned& a, unsigned& b) {
#if __has_builtin(__builtin_amdgcn_permlane16_swap)
    typedef unsigned u32x2 __attribute__((ext_vector_type(2)));
    u32x2 r = __builtin_amdgcn_permlane16_swap(a, b, false, false);
    a = r[0]; b = r[1];
#else
    const bool up = (threadIdx.x & 16) != 0;
    unsigned as = (unsigned)__shfl_xor((int)a, 16);
    unsigned bs = (unsigned)__shfl_xor((int)b, 16);
    unsigned na = up ? bs : a;
    unsigned nb = up ? b : as;
    a = na; b = nb;
#endif
}

// ---------------- prepass: fp32 -> bf16 (x, W_qkv, W_out) -------------------------
__global__ __launch_bounds__(256) void cvt_all(const float* __restrict__ x,
                                               const float* __restrict__ wq,
                                               const float* __restrict__ wo,
                                               u16* __restrict__ xb,
                                               u16* __restrict__ wqb,
                                               u16* __restrict__ wob) {
    const int nx8 = 8388608 / 8, nq8 = 3145728 / 8, no8 = 1048576 / 8;
    const int n8 = nx8 + nq8 + no8;
    for (int i = blockIdx.x * blockDim.x + threadIdx.x; i < n8;
         i += gridDim.x * blockDim.x) {
        const float* src;
        u16* dst;
        if (i < nx8)            { src = x  + (size_t)i * 8;          dst = xb  + (size_t)i * 8; }
        else if (i < nx8 + nq8) { size_t j = i - nx8; src = wq + j * 8; dst = wqb + j * 8; }
        else                    { size_t j = i - nx8 - nq8; src = wo + j * 8; dst = wob + j * 8; }
        floatx4 a = *(const floatx4*)src;
        floatx4 b = *(const floatx4*)(src + 4);
        union { bf16x8 v; unsigned u[4]; } r;
        r.u[0] = pkbf(a[0], a[1]); r.u[1] = pkbf(a[2], a[3]);
        r.u[2] = pkbf(b[0], b[1]); r.u[3] = pkbf(b[2], b[3]);
        *(bf16x8*)dst = r.v;
    }
}

// ---------------- GEMM (bf16 inputs, gll16 staging, 2-phase dbuf) -----------------
// SCATTER=1: prescales q channels (r<64) by CEXP for the attn exp2 fold.
// QSLOT=1: A gathered from q-slots (fallback path only).
template <int SCATTER, int QSLOT>
__global__ __launch_bounds__(256) void gemm_lds(const u16* __restrict__ Ab,
                                                const u16* __restrict__ Bb,
                                                const float* __restrict__ bias,
                                                void* __restrict__ Cv,
                                                int K, int N) {
    __shared__ u16 As[2][128 * 64];   // 32 KB (2 buffers)
    __shared__ u16 Bs[2][128 * 64];   // 32 KB

    const int tid  = threadIdx.x;
    const int lane = tid & 63;
    const int wave = tid >> 6;
    const int quad = lane >> 4;
    const int l15  = lane & 15;
    const int wm   = (wave >> 1) * 64;
    const int wn   = (wave & 1) * 64;
    const int blockM = blockIdx.y * 128;
    const int blockN = blockIdx.x * 128;

    floatx4 acc[4][4];
#pragma unroll
    for (int i = 0; i < 4; i++)
#pragma unroll
        for (int j = 0; j < 4; j++) acc[i][j] = (floatx4){0.f, 0.f, 0.f, 0.f};

    const int lr = lane >> 3;                       // row within 8-row chunk
    const int scol = ((lane & 7) ^ (lr & 7)) * 8;   // inverse-swizzled source col

    auto stage = [&](int buf, int k0) {
#pragma unroll
        for (int i = 0; i < 4; i++) {
            const int c = wave * 4 + i;             // chunk 0..15
            const int row = blockM + c * 8 + lr;
            const u16* src;
            if (QSLOT) {   // A = att_v in q-slots: k0 selects head (BK==hs==64)
                const int b = row >> 11, t = row & 2047, h = k0 >> 6;
                src = Ab + ((size_t)((b * HH + h) * TT + t)) * 192 + scol;
            } else {
                src = Ab + (size_t)row * K + k0 + scol;
            }
            gll16(src, &As[buf][c * 512]);
        }
#pragma unroll
        for (int i = 0; i < 4; i++) {
            const int c = wave * 4 + i;
            const int row = blockN + c * 8 + lr;
            gll16(Bb + (size_t)row * K + k0 + scol, &Bs[buf][c * 512]);
        }
    };

    stage(0, 0);
    __syncthreads();   // implicit vmcnt(0): buf0 ready

    int cur = 0;
    for (int k0 = 0; k0 < K; k0 += 64) {
        if (k0 + 64 < K) stage(cur ^ 1, k0 + 64);   // DMA next tile -> other buf

#pragma unroll
        for (int ks = 0; ks < 2; ks++) {
            const int slot = ks * 4 + quad;
            bf16x8 af[4], bfr[4];
#pragma unroll
            for (int mi = 0; mi < 4; mi++)
                af[mi] = *(const bf16x8*)&As[cur][sw8(wm + mi * 16 + l15, slot)];
#pragma unroll
            for (int ni = 0; ni < 4; ni++)
                bfr[ni] = *(const bf16x8*)&Bs[cur][sw8(wn + ni * 16 + l15, slot)];
#pragma unroll
            for (int mi = 0; mi < 4; mi++)
#pragma unroll
                for (int ni = 0; ni < 4; ni++)
                    acc[mi][ni] = __builtin_amdgcn_mfma_f32_16x16x32_bf16(
                        af[mi], bfr[ni], acc[mi][ni], 0, 0, 0);
        }

        __syncthreads();   // drains my DMA + all waves' reads of cur
        cur ^= 1;
    }

    // epilogue: C/D layout col = lane&15, row = quad*4 + reg
#pragma unroll
    for (int ni = 0; ni < 4; ni++) {
        const int col = blockN + wn + ni * 16 + l15;
        const float bv = bias[col];
        if (SCATTER) {
            const int h = col / 192;
            const int r = col - h * 192;
            const float qs = (r < 64) ? CEXP : 1.0f;   // prescale q channels
            u16* C = (u16*)Cv;
#pragma unroll
            for (int mi = 0; mi < 4; mi++)
#pragma unroll
                for (int reg = 0; reg < 4; reg++) {
                    const int row = blockM + wm + mi * 16 + quad * 4 + reg;
                    const int b = row >> 11, t = row & 2047;
                    C[((size_t)((b * HH + h) * TT + t)) * 192 + r] =
                        f2bf((acc[mi][ni][reg] + bv) * qs);
                }
        } else {
            float* C = (float*)Cv;
#pragma unroll
            for (int mi = 0; mi < 4; mi++)
#pragma unroll
                for (int reg = 0; reg < 4; reg++) {
                    const int row = blockM + wm + mi * 16 + quad * 4 + reg;
                    C[(size_t)row * N + col] = acc[mi][ni][reg] + bv;
                }
        }
    }
}

// ---------------- GEMM fallback (fp32 inputs, register staging) -------------------
template <int SCATTER, int QSLOT>
__global__ __launch_bounds__(256) void gemm_bt(const void* __restrict__ Av,
                                               const float* __restrict__ Bw,
                                               const float* __restrict__ bias,
                                               void* __restrict__ Cv,
                                               int K, int N) {
    __shared__ u16 As[128 * 64];
    __shared__ u16 Bs[128 * 64];

    const int tid  = threadIdx.x;
    const int lane = tid & 63;
    const int wave = tid >> 6;
    const int quad = lane >> 4;
    const int l15  = lane & 15;
    const int wm   = (wave >> 1) * 64;
    const int wn   = (wave & 1) * 64;
    const int blockM = blockIdx.y * 128;
    const int blockN = blockIdx.x * 128;

    floatx4 acc[4][4];
#pragma unroll
    for (int i = 0; i < 4; i++)
#pragma unroll
        for (int j = 0; j < 4; j++) acc[i][j] = (floatx4){0.f, 0.f, 0.f, 0.f};

    const int srow = lane >> 3;
    const int scol = (lane & 7) * 8;

    for (int k0 = 0; k0 < K; k0 += 64) {
        bf16x8 at[4], bt[4];
#pragma unroll
        for (int i = 0; i < 4; i++) {
            const int row = blockM + (i * 4 + wave) * 8 + srow;
            if (QSLOT) {
                const int b = row >> 11, t = row & 2047, h = k0 >> 6;
                at[i] = *(const bf16x8*)((const u16*)Av
                         + ((size_t)((b * HH + h) * TT + t)) * 192 + scol);
            } else {
                at[i] = cvt8((const float*)Av + (size_t)row * K + k0 + scol);
            }
        }
#pragma unroll
        for (int i = 0; i < 4; i++)
            bt[i] = cvt8(Bw + (size_t)(blockN + (i * 4 + wave) * 8 + srow) * K + k0 + scol);

        __syncthreads();
#pragma unroll
        for (int i = 0; i < 4; i++)
            *(bf16x8*)&As[sw8((i * 4 + wave) * 8 + srow, lane & 7)] = at[i];
#pragma unroll
        for (int i = 0; i < 4; i++)
            *(bf16x8*)&Bs[sw8((i * 4 + wave) * 8 + srow, lane & 7)] = bt[i];
        __syncthreads();

#pragma unroll
        for (int ks = 0; ks < 2; ks++) {
            const int slot = ks * 4 + quad;
            bf16x8 af[4], bfr[4];
#pragma unroll
            for (int mi = 0; mi < 4; mi++)
                af[mi] = *(const bf16x8*)&As[sw8(wm + mi * 16 + l15, slot)];
#pragma unroll
            for (int ni = 0; ni < 4; ni++)
                bfr[ni] = *(const bf16x8*)&Bs[sw8(wn + ni * 16 + l15, slot)];
#pragma unroll
            for (int mi = 0; mi < 4; mi++)
#pragma unroll
                for (int ni = 0; ni < 4; ni++)
                    acc[mi][ni] = __builtin_amdgcn_mfma_f32_16x16x32_bf16(
                        af[mi], bfr[ni], acc[mi][ni], 0, 0, 0);
        }
    }

#pragma unroll
    for (int ni = 0; ni < 4; ni++) {
        const int col = blockN + wn + ni * 16 + l15;
        const float bv = bias[col];
        if (SCATTER) {
            const int h = col / 192;
            const int r = col - h * 192;
            const float qs = (r < 64) ? CEXP : 1.0f;
            u16* C = (u16*)Cv;
#pragma unroll
            for (int mi = 0; mi < 4; mi++)
#pragma unroll
                for (int reg = 0; reg < 4; reg++) {
                    const int row = blockM + wm + mi * 16 + quad * 4 + reg;
                    const int b = row >> 11, t = row & 2047;
                    C[((size_t)((b * HH + h) * TT + t)) * 192 + r] =
                        f2bf((acc[mi][ni][reg] + bv) * qs);
                }
        } else {
            float* C = (float*)Cv;
#pragma unroll
            for (int mi = 0; mi < 4; mi++)
#pragma unroll
                for (int reg = 0; reg < 4; reg++) {
                    const int row = blockM + wm + mi * 16 + quad * 4 + reg;
                    C[(size_t)row * N + col] = acc[mi][ni][reg] + bv;
                }
        }
    }
}

// ---------------- Flash attention (R28: 8 waves x 32 q-rows, swapped QK^T) --------
// 512 threads, 256-row Q tile, Bc=64. Q pre-scaled by CEXP. K: 1 gll16/thread.
// V: 8 u16 transpose-writes/thread. Row-sum l via MFMA vs ones. Zero-C init.
// avd != nullptr: write att_v DENSE [b*T+t][h*64+d]; else in-place q-slot.
__global__ __launch_bounds__(512) void attn_fwd(u16* __restrict__ qkv,
                                                u16* __restrict__ avd) {
    __shared__ u16 Ks[64 * 64];        // 8 KB  K-tile  [s][d]   (swizzled)
    __shared__ u16 Vts[64 * 64];       // 8 KB  V-tile transposed [d][s] (swizzled)

    const int tid  = threadIdx.x;
    const int lane = tid & 63;
    const int wave = tid >> 6;         // 0..7
    const int quad = lane >> 4;
    const int l15  = lane & 15;

    const int bh = blockIdx.y;
    const int t0 = blockIdx.x * 256;
    u16* Qg = qkv + (size_t)bh * TT * 192;

    bf16x8 qf[2][2];
#pragma unroll
    for (int qi = 0; qi < 2; qi++) {
        const int trow = t0 + wave * 32 + qi * 16 + l15;
#pragma unroll
        for (int ks = 0; ks < 2; ks++)
            qf[qi][ks] = *(const bf16x8*)(Qg + (size_t)trow * 192 + ks * 32 + quad * 8);
    }

    bf16x8 ones;
#pragma unroll
    for (int j = 0; j < 8; j++) ones[j] = (short)0x3F80;   // bf16 1.0
    const floatx4 zero4 = (floatx4){0.f, 0.f, 0.f, 0.f};

    floatx4 o[2][4];
#pragma unroll
    for (int qi = 0; qi < 2; qi++)
#pragma unroll
        for (int di = 0; di < 4; di++) o[qi][di] = (floatx4){0.f, 0.f, 0.f, 0.f};
    floatx4 l_acc[2] = {(floatx4){0.f,0.f,0.f,0.f}, (floatx4){0.f,0.f,0.f,0.f}};

    const int lr = lane >> 3;
    const int scolsw = ((lane & 7) ^ (lr & 7)) * 8;   // inverse-swizzled col
    const int vs  = tid & 63;          // V staging: s = tid&63
    const int vd0 = (tid >> 6) * 8;    // V staging: 8-d band per wave

    for (int s0 = 0; s0 < TT; s0 += 64) {
        // V loads into registers before the barrier (no LDS hazard)
        bf16x8 v0 = *(const bf16x8*)(Qg + (size_t)(s0 + vs) * 192 + 128 + vd0);

        __syncthreads();   // previous iteration's Ks/Vts readers done
        // K via async DMA (1 chunk/wave); V scalar writes overlap the DMA
        gll16(Qg + (size_t)(s0 + wave * 8 + lr) * 192 + 64 + scolsw,
              &Ks[wave * 512]);
        {
            const int vslot = vs >> 3, voff = vs & 7;
#pragma unroll
            for (int j = 0; j < 8; j++) {
                const int row = vd0 + j;
                Vts[row * 64 + (((vslot ^ (row & 7)) & 7) << 3) + voff] = (u16)v0[j];
            }
        }
        __syncthreads();   // drains vmcnt (K DMA) + lgkm (V writes)

        // S^T = K @ Q' : lane = S'[s=si*16+quad*4+reg][q=wave*32+qi*16+l15]
        floatx4 s_acc[4][2];
        __builtin_amdgcn_s_setprio(1);
        {
            bf16x8 kf[4];
#pragma unroll
            for (int si = 0; si < 4; si++)
                kf[si] = *(const bf16x8*)&Ks[sw8(si * 16 + l15, quad)];
#pragma unroll
            for (int si = 0; si < 4; si++)
#pragma unroll
                for (int qi = 0; qi < 2; qi++)
                    s_acc[si][qi] = __builtin_amdgcn_mfma_f32_16x16x32_bf16(
                        kf[si], qf[qi][0], zero4, 0, 0, 0);
        }
        {
            bf16x8 kf[4];
#pragma unroll
            for (int si = 0; si < 4; si++)
                kf[si] = *(const bf16x8*)&Ks[sw8(si * 16 + l15, 4 + quad)];
#pragma unroll
            for (int si = 0; si < 4; si++)
#pragma unroll
                for (int qi = 0; qi < 2; qi++)
                    s_acc[si][qi] = __builtin_amdgcn_mfma_f32_16x16x32_bf16(
                        kf[si], qf[qi][1], s_acc[si][qi], 0, 0, 0);
        }
        __builtin_amdgcn_s_setprio(0);

        // P = exp2(S') in-register; pack bf16 pairs (no mul — Q pre-scaled)
        unsigned c[4][2][2];
#pragma unroll
        for (int si = 0; si < 4; si++)
#pragma unroll
            for (int qi = 0; qi < 2; qi++) {
                floatx4 p;
#pragma unroll
                for (int r = 0; r < 4; r++) p[r] = EXP2(s_acc[si][qi][r]);
                c[si][qi][0] = pkbf(p[0], p[1]);
                c[si][qi][1] = pkbf(p[2], p[3]);
            }

        // redistribute C/D-layout P -> A-fragments pf[qi][ks]
        union PF { bf16x8 v; unsigned u[4]; } pf[2][2];
#pragma unroll
        for (int qi = 0; qi < 2; qi++)
#pragma unroll
            for (int ks = 0; ks < 2; ks++)
#pragma unroll
                for (int h = 0; h < 2; h++) {
                    unsigned a = c[2 * ks][qi][h];
                    unsigned b = c[2 * ks + 1][qi][h];
                    pl32swap(a, b);
                    pl16swap(a, b);
                    pf[qi][ks].u[h]     = a;
                    pf[qi][ks].u[2 + h] = b;
                }

        // O += P @ V ; l += P @ ones (row-sum on the MFMA pipe)
        __builtin_amdgcn_s_setprio(1);
#pragma unroll
        for (int ks = 0; ks < 2; ks++) {
            const int slot = ks * 4 + quad;
            bf16x8 vf[4];
#pragma unroll
            for (int di = 0; di < 4; di++)
                vf[di] = *(const bf16x8*)&Vts[sw8(di * 16 + l15, slot)];
#pragma unroll
            for (int qi = 0; qi < 2; qi++) {
#pragma unroll
                for (int di = 0; di < 4; di++)
                    o[qi][di] = __builtin_amdgcn_mfma_f32_16x16x32_bf16(
                        pf[qi][ks].v, vf[di], o[qi][di], 0, 0, 0);
                l_acc[qi] = __builtin_amdgcn_mfma_f32_16x16x32_bf16(
                    pf[qi][ks].v, ones, l_acc[qi], 0, 0, 0);
            }
        }
        __builtin_amdgcn_s_setprio(0);
    }

    // normalize, write att_v (bf16) — dense layout if avd, else q-slot in place.
    if (avd) {
        const int b = bh >> 4, h = bh & 15;
        u16* D = avd + (size_t)b * TT * CC + h * 64;
#pragma unroll
        for (int qi = 0; qi < 2; qi++)
#pragma unroll
            for (int reg = 0; reg < 4; reg++) {
                const float inv_l = 1.0f / l_acc[qi][reg];
                const int trow = t0 + wave * 32 + qi * 16 + quad * 4 + reg;
#pragma unroll
                for (int di = 0; di < 4; di++)
                    D[(size_t)trow * CC + di * 16 + l15] = f2bf(o[qi][di][reg] * inv_l);
            }
    } else {
#pragma unroll
        for (int qi = 0; qi < 2; qi++)
#pragma unroll
            for (int reg = 0; reg < 4; reg++) {
                const float inv_l = 1.0f / l_acc[qi][reg];
                const int trow = t0 + wave * 32 + qi * 16 + quad * 4 + reg;
#pragma unroll
                for (int di = 0; di < 4; di++)
                    Qg[(size_t)trow * 192 + di * 16 + l15] = f2bf(o[qi][di][reg] * inv_l);
            }
    }
}

extern "C" void kernel_launch(void* const* d_in, const int* in_sizes, int n_in,
                              void* d_out, int out_size, void* d_ws, size_t ws_size,
                              hipStream_t stream) {
    (void)out_size;
    float* out = (float*)d_out;

    const float *x = nullptr, *wq = nullptr, *bq = nullptr, *wo = nullptr, *bo = nullptr;
    int found = 0;
    for (int i = 0; i < n_in && i < 8; i++) {
        switch (in_sizes[i]) {
            case 8388608: x  = (const float*)d_in[i]; found |= 1;  break;
            case 3145728: wq = (const float*)d_in[i]; found |= 2;  break;
            case 3072:    bq = (const float*)d_in[i]; found |= 4;  break;
            case 1048576: wo = (const float*)d_in[i]; found |= 8;  break;
            case 1024:    bo = (const float*)d_in[i]; found |= 16; break;
        }
    }
    if (found != 31) {
        x  = (const float*)d_in[0]; wq = (const float*)d_in[1];
        bq = (const float*)d_in[2]; wo = (const float*)d_in[3];
        bo = (const float*)d_in[4];
    }

    u16* qkv = (u16*)d_ws;   // 48 MiB qkv ws

    const dim3 g1(3 * CC / 128, BB * TT / 128), ga(TT / 256, BB * HH),
               g3(CC / 128, BB * TT / 128);

    if (ws_size >= 92274688u) {   // 88 MiB: qkv48 + xb16 + wqb6 + wob2 + avd16
        u16* xb  = qkv + 25165824;   // 48 MiB
        u16* wqb = qkv + 33554432;   // 64 MiB
        u16* wob = qkv + 36700160;   // 70 MiB
        u16* avd = qkv + 37748736;   // 72 MiB (8192x1024 bf16 = 16 MiB)
        cvt_all<<<2048, 256, 0, stream>>>(x, wq, wo, xb, wqb, wob);
        gemm_lds<1, 0><<<g1, 256, 0, stream>>>(xb, wqb, bq, qkv, CC, 3 * CC);
        attn_fwd<<<ga, 512, 0, stream>>>(qkv, avd);
        gemm_lds<0, 0><<<g3, 256, 0, stream>>>(avd, wob, bo, out, CC, CC);
    } else if (ws_size >= 75497472u) {   // 72 MiB path (q-slot gather gemm3)
        u16* xb  = qkv + 25165824;
        u16* wqb = qkv + 33554432;
        u16* wob = qkv + 36700160;
        cvt_all<<<2048, 256, 0, stream>>>(x, wq, wo, xb, wqb, wob);
        gemm_lds<1, 0><<<g1, 256, 0, stream>>>(xb, wqb, bq, qkv, CC, 3 * CC);
        attn_fwd<<<ga, 512, 0, stream>>>(qkv, nullptr);
        gemm_lds<0, 1><<<g3, 256, 0, stream>>>(qkv, wob, bo, out, CC, CC);
    } else {                              // register-staged fallback
        gemm_bt<1, 0><<<g1, 256, 0, stream>>>(x, wq, bq, qkv, CC, 3 * CC);
        attn_fwd<<<ga, 512, 0, stream>>>(qkv, nullptr);
        gemm_bt<0, 1><<<g3, 256, 0, stream>>>(qkv, wo, bo, out, CC, CC);
    }
}